// Round 1
// baseline (305.671 us; speedup 1.0000x reference)
//
#include <hip/hip_runtime.h>

// Problem constants
#define NN 64
#define CC 64
#define TT 256
#define VV 25
#define RR 8
#define OO 64
#define PLANE 6400  // T*V per (n,c)

// ---------------------------------------------------------------------------
// Kernel A: xsum[n][c][v] = sum_t x[n][c][t][v]
// One block per (n,c). Stage the 6400-float plane in LDS coalesced, reduce.
// ---------------------------------------------------------------------------
__global__ __launch_bounds__(256) void k_xsum(const float* __restrict__ x,
                                              float* __restrict__ xsum) {
  int nc = blockIdx.x;  // n*64 + c
  const float* src = x + (size_t)nc * PLANE;
  __shared__ float s[PLANE];
  int tid = threadIdx.x;
#pragma unroll
  for (int k = 0; k < 25; ++k) s[k * 256 + tid] = src[k * 256 + tid];
  __syncthreads();
  if (tid < VV) {
    float a0 = 0.f, a1 = 0.f, a2 = 0.f, a3 = 0.f;
    for (int t = 0; t < TT; t += 4) {
      a0 += s[(t + 0) * VV + tid];
      a1 += s[(t + 1) * VV + tid];
      a2 += s[(t + 2) * VV + tid];
      a3 += s[(t + 3) * VV + tid];
    }
    xsum[nc * VV + tid] = (a0 + a1) + (a2 + a3);
  }
}

// ---------------------------------------------------------------------------
// Kernel T: w3t[c][o] = w3[o][c]  (so conv3's inner loop reads contiguous,
// wave-uniform weights -> s_load_dwordx16)
// ---------------------------------------------------------------------------
__global__ void k_wt(const float* __restrict__ w3, float* __restrict__ w3t) {
  int k = blockIdx.x * 256 + threadIdx.x;  // < 4096
  if (k < 4096) {
    int c = k >> 6, o = k & 63;
    w3t[k] = w3[o * 64 + c];
  }
}

// ---------------------------------------------------------------------------
// Kernel B: build m (padded to [n][o][u][32]) from xsum.
// x1[r][v] = (sum_c w1[r][c]*xsum[c][v])/T + b1[r]  (same for x2)
// att[r][u][v] = tanh(x1[r][u] - x2[r][v])
// m[o][u][v] = sum_r w4[o][r]*att[r][u][v] + b4[o] + A[u][v]   (ALPHA = 1)
// ---------------------------------------------------------------------------
__global__ __launch_bounds__(256) void k_build_m(
    const float* __restrict__ xsum, const float* __restrict__ A,
    const float* __restrict__ w1, const float* __restrict__ b1,
    const float* __restrict__ w2, const float* __restrict__ b2,
    const float* __restrict__ w4, const float* __restrict__ b4,
    float* __restrict__ mp) {
  int n = blockIdx.x;
  __shared__ float xs[CC * VV];    // 1600
  __shared__ float sx1[RR * VV];   // 200
  __shared__ float sx2[RR * VV];   // 200
  __shared__ float att[RR * 625];  // 5000
  int tid = threadIdx.x;
  const float* xsn = xsum + n * (CC * VV);
  for (int k = tid; k < CC * VV; k += 256) xs[k] = xsn[k];
  __syncthreads();
  if (tid < RR * VV) {
    int r = tid / VV, v = tid % VV;
    float a1 = 0.f, a2 = 0.f;
#pragma unroll
    for (int c = 0; c < CC; ++c) {
      float xv = xs[c * VV + v];
      a1 = fmaf(w1[r * CC + c], xv, a1);
      a2 = fmaf(w2[r * CC + c], xv, a2);
    }
    sx1[tid] = a1 * (1.f / 256.f) + b1[r];
    sx2[tid] = a2 * (1.f / 256.f) + b2[r];
  }
  __syncthreads();
  for (int k = tid; k < RR * 625; k += 256) {
    int r = k / 625, uv = k % 625;
    int u = uv / VV, v = uv % VV;
    att[k] = tanhf(sx1[r * VV + u] - sx2[r * VV + v]);
  }
  __syncthreads();
  for (int k = tid; k < OO * 625; k += 256) {
    int o = k / 625, uv = k % 625;
    int u = uv / VV, v = uv % VV;
    float a = b4[o] + A[uv];
#pragma unroll
    for (int r = 0; r < RR; ++r) a = fmaf(w4[o * RR + r], att[r * 625 + uv], a);
    mp[(((size_t)n * OO + o) * VV + u) * 32 + v] = a;
  }
}

// ---------------------------------------------------------------------------
// Kernel C: x3[n][o][p] = sum_c w3t[c][o] * x[n][c][p] + b3[o], p = t*25+v.
// Thread per (n,p) point; 64 fp32 accumulators; weights via scalar loads.
// Writes into d_out (re-used as x3 buffer; same size as out).
// ---------------------------------------------------------------------------
__global__ __launch_bounds__(256) void k_conv3(const float* __restrict__ x,
                                               const float* __restrict__ w3t,
                                               const float* __restrict__ b3,
                                               float* __restrict__ x3) {
  int n = blockIdx.y;
  int p = blockIdx.x * 256 + threadIdx.x;  // < 6400
  const float* xn = x + (size_t)n * CC * PLANE;
  float acc[OO];
#pragma unroll
  for (int o = 0; o < OO; ++o) acc[o] = b3[o];
#pragma unroll 2
  for (int c = 0; c < CC; ++c) {
    float xv = xn[(size_t)c * PLANE + p];
    const float* w = w3t + c * OO;
#pragma unroll
    for (int o = 0; o < OO; ++o) acc[o] = fmaf(w[o], xv, acc[o]);
  }
  float* dst = x3 + (size_t)n * OO * PLANE + p;
#pragma unroll
  for (int o = 0; o < OO; ++o) dst[(size_t)o * PLANE] = acc[o];
}

// ---------------------------------------------------------------------------
// Kernel D: out[n][o][t][u] = sum_v m[n][o][u][v] * x3[n][o][t][v], in place.
// Block per (n,o): stage the 6400-float plane in LDS; each thread owns row t.
// Stride-25 LDS accesses are conflict-free mod 32. m via wave-uniform s_loads.
// ---------------------------------------------------------------------------
__global__ __launch_bounds__(256) void k_aggr(float* __restrict__ out,
                                              const float* __restrict__ mp) {
  int no = blockIdx.x;  // n*64 + o
  float* base = out + (size_t)no * PLANE;
  __shared__ float s[PLANE];
  int tid = threadIdx.x;
#pragma unroll
  for (int k = 0; k < 25; ++k) s[k * 256 + tid] = base[k * 256 + tid];
  __syncthreads();
  const float* m = mp + (size_t)no * (VV * 32);
  float xr[VV], orow[VV];
#pragma unroll
  for (int v = 0; v < VV; ++v) xr[v] = s[tid * VV + v];
#pragma unroll
  for (int u = 0; u < VV; ++u) {
    float a = 0.f;
#pragma unroll
    for (int v = 0; v < VV; ++v) a = fmaf(m[u * 32 + v], xr[v], a);
    orow[u] = a;
  }
  // Each thread reads/writes only its own row -> no barrier needed here.
#pragma unroll
  for (int u = 0; u < VV; ++u) s[tid * VV + u] = orow[u];
  __syncthreads();
#pragma unroll
  for (int k = 0; k < 25; ++k) base[k * 256 + tid] = s[k * 256 + tid];
}

extern "C" void kernel_launch(void* const* d_in, const int* in_sizes, int n_in,
                              void* d_out, int out_size, void* d_ws,
                              size_t ws_size, hipStream_t stream) {
  const float* x = (const float*)d_in[0];
  const float* A = (const float*)d_in[1];
  const float* w1 = (const float*)d_in[2];
  const float* b1 = (const float*)d_in[3];
  const float* w2 = (const float*)d_in[4];
  const float* b2 = (const float*)d_in[5];
  const float* w3 = (const float*)d_in[6];
  const float* b3 = (const float*)d_in[7];
  const float* w4 = (const float*)d_in[8];
  const float* b4 = (const float*)d_in[9];
  float* out = (float*)d_out;
  float* ws = (float*)d_ws;

  float* xsum = ws;            // 64*64*25      = 102400 floats
  float* w3t = ws + 102400;    // 4096 floats
  float* mp = ws + 106496;     // 64*64*25*32   = 3276800 floats (13.1 MB total)

  k_xsum<<<NN * CC, 256, 0, stream>>>(x, xsum);
  k_wt<<<16, 256, 0, stream>>>(w3, w3t);
  k_build_m<<<NN, 256, 0, stream>>>(xsum, A, w1, b1, w2, b2, w4, b4, mp);
  k_conv3<<<dim3(PLANE / 256, NN), 256, 0, stream>>>(x, w3t, b3, out);
  k_aggr<<<NN * OO, 256, 0, stream>>>(out, mp);
}